// Round 5
// baseline (1437.477 us; speedup 1.0000x reference)
//
#include <hip/hip_runtime.h>
#include <hip/hip_cooperative_groups.h>
namespace cg = cooperative_groups;

// RouteNet f32: BN(x) -> 2 input GEMMs -> 16-bank gated graph (cooperative, acts in LDS)
// -> output GEMM. BN folded into B'=scale*W_in, bias'=b_in+shift@W_in.
// Bank acts raw (post-relu, pre-BN); normalized on the fly from slot-sharded stats.

#define BATCH 8192
#define NIN 3072
#define DD 32
#define NB 16
#define NOUT 1000
#define TGOFF (BATCH * NOUT)
#define BNEPS 1e-5f

// ws float offsets
#define O_SUM 0          // [3072]
#define O_SUM2 3072      // [3072]
#define O_STATS2 6144    // [16 banks][16 slots][64] = 16384
#define O_TG 22528       // [8192]
#define O_ACC 30720      // [8192*64] GEMM partial accumulator
#define ZERO_FLOATS 555008
#define O_SCALE 555008   // [3072]
#define O_SHIFT 558080   // [3072]
#define O_BIAS 561152    // [64]
#define O_BP 561216      // [3072][64] folded B'
#define O_ACTS 757824    // [2][8192][32] raw input-bank acts
#define O_ACTS14 1282112 // [2][8192][32] raw bank-14/15 acts
// total 1,806,400 floats (~7.2 MB)

// ---- K1: column stats of x ----
__global__ void __launch_bounds__(256) k_stats(const float* __restrict__ x, float* __restrict__ ws) {
    int c = blockIdx.x * 256 + threadIdx.x;
    const float* p = x + (size_t)blockIdx.y * 64 * NIN + c;
    float s = 0.f, s2 = 0.f;
#pragma unroll 8
    for (int i = 0; i < 64; i++) { float v = p[(size_t)i * NIN]; s += v; s2 += v * v; }
    atomicAdd(&ws[O_SUM + c], s);
    atomicAdd(&ws[O_SUM2 + c], s2);
}

// ---- K2: scale/shift; seed fused bias with b_in ----
__global__ void __launch_bounds__(256) k_prep(float* __restrict__ ws, const float* __restrict__ g,
                                              const float* __restrict__ b, const float* __restrict__ b_in) {
    int c = blockIdx.x * 256 + threadIdx.x;
    float mean = ws[O_SUM + c] * (1.f / BATCH);
    float var = ws[O_SUM2 + c] * (1.f / BATCH) - mean * mean;
    float sc = g[c] * rsqrtf(fmaxf(var, 0.f) + BNEPS);
    ws[O_SCALE + c] = sc;
    ws[O_SHIFT + c] = b[c] - mean * sc;
    if (c < 64) ws[O_BIAS + c] = b_in[c];
}

// ---- K3a: bias' += shift @ W_in ----
__global__ void __launch_bounds__(256) k_bias(float* __restrict__ ws, const float* __restrict__ W_in) {
    int bank = blockIdx.x & 1, jc = blockIdx.x >> 1;
    int d = threadIdx.x & 31, js = threadIdx.x >> 5;
    int j0 = jc * 256 + js * 32;
    float a = 0.f;
    for (int j = 0; j < 32; j++)
        a += ws[O_SHIFT + j0 + j] * W_in[(size_t)bank * NIN * DD + (size_t)(j0 + j) * DD + d];
    __shared__ float red[8][32];
    red[js][d] = a;
    __syncthreads();
    if (threadIdx.x < 32) {
        float t = 0.f;
#pragma unroll
        for (int g8 = 0; g8 < 8; g8++) t += red[g8][threadIdx.x];
        atomicAdd(&ws[O_BIAS + bank * 32 + threadIdx.x], t);
    }
}

// ---- K3b: B'[j][c] = scale[j] * W_in[c>>5][j][c&31] ----
__global__ void __launch_bounds__(256) k_bfold(float* __restrict__ ws, const float* __restrict__ W_in) {
    int idx = blockIdx.x * 256 + threadIdx.x;
    int j = idx >> 6, c = idx & 63;
    ws[O_BP + idx] = ws[O_SCALE + j] * W_in[(size_t)(c >> 5) * NIN * DD + (size_t)j * DD + (c & 31)];
}

// ---- K4: input GEMM, 4r x 4c per thread, 2-way K-split, atomic f32 partials ----
__global__ void __launch_bounds__(128) k_gemm2(const float* __restrict__ x, float* __restrict__ ws) {
    __shared__ float xL[32][36];
    __shared__ float bL[32][64];
    int tid = threadIdx.x;
    int row0 = blockIdx.x * 32;
    int k00 = blockIdx.y * 1536;
    const float* bp = ws + O_BP;
    float acc[4][4] = {};
    int lr = tid >> 2, lq = tid & 3;
    int rt = tid >> 4, tx = tid & 15;
    for (int kc = 0; kc < 48; kc++) {
        int k0 = k00 + kc * 32;
        float4 xa = *(const float4*)&x[(size_t)(row0 + lr) * NIN + k0 + lq * 8];
        float4 xb = *(const float4*)&x[(size_t)(row0 + lr) * NIN + k0 + lq * 8 + 4];
        float4 b0 = *(const float4*)&bp[(size_t)(k0 + lr) * 64 + lq * 16];
        float4 b1 = *(const float4*)&bp[(size_t)(k0 + lr) * 64 + lq * 16 + 4];
        float4 b2 = *(const float4*)&bp[(size_t)(k0 + lr) * 64 + lq * 16 + 8];
        float4 b3 = *(const float4*)&bp[(size_t)(k0 + lr) * 64 + lq * 16 + 12];
        __syncthreads();
        *(float4*)&xL[lr][lq * 8] = xa;
        *(float4*)&xL[lr][lq * 8 + 4] = xb;
        *(float4*)&bL[lr][lq * 16] = b0;
        *(float4*)&bL[lr][lq * 16 + 4] = b1;
        *(float4*)&bL[lr][lq * 16 + 8] = b2;
        *(float4*)&bL[lr][lq * 16 + 12] = b3;
        __syncthreads();
#pragma unroll
        for (int kk = 0; kk < 32; kk += 4) {
            float4 bv0 = *(float4*)&bL[kk][tx * 4];
            float4 bv1 = *(float4*)&bL[kk + 1][tx * 4];
            float4 bv2 = *(float4*)&bL[kk + 2][tx * 4];
            float4 bv3 = *(float4*)&bL[kk + 3][tx * 4];
#pragma unroll
            for (int j = 0; j < 4; j++) {
                float4 xv = *(float4*)&xL[rt * 4 + j][kk];
                acc[j][0] += xv.x * bv0.x + xv.y * bv1.x + xv.z * bv2.x + xv.w * bv3.x;
                acc[j][1] += xv.x * bv0.y + xv.y * bv1.y + xv.z * bv2.y + xv.w * bv3.y;
                acc[j][2] += xv.x * bv0.z + xv.y * bv1.z + xv.z * bv2.z + xv.w * bv3.z;
                acc[j][3] += xv.x * bv0.w + xv.y * bv1.w + xv.z * bv2.w + xv.w * bv3.w;
            }
        }
    }
#pragma unroll
    for (int j = 0; j < 4; j++)
#pragma unroll
        for (int i = 0; i < 4; i++)
            atomicAdd(&ws[O_ACC + (size_t)(row0 + rt * 4 + j) * 64 + tx * 4 + i], acc[j][i]);
}

// ---- K5: bias + relu + reshape into acts[2][8192][32] ----
__global__ void __launch_bounds__(256) k_act(float* __restrict__ ws) {
    int i4 = (blockIdx.x * 256 + threadIdx.x) * 4;
    float4 a = *(float4*)&ws[O_ACC + i4];
    int c = i4 & 63, row = i4 >> 6;
    const float* bias = ws + O_BIAS;
    float4 v;
    v.x = fmaxf(a.x + bias[c], 0.f);
    v.y = fmaxf(a.y + bias[c + 1], 0.f);
    v.z = fmaxf(a.z + bias[c + 2], 0.f);
    v.w = fmaxf(a.w + bias[c + 3], 0.f);
    int bank = c >> 5, dd = c & 31;
    *(float4*)&ws[O_ACTS + ((size_t)bank * BATCH + row) * DD + dd] = v;
}

// ---- K6: cooperative bank graph. 512 blocks x 16 rows; acts slab lives in LDS. ----
__global__ void __launch_bounds__(256) k_graph(float* __restrict__ ws, const float* __restrict__ Wg,
                                               const float* __restrict__ Wd, const float* __restrict__ bd) {
    cg::grid_group grid = cg::this_grid();
    __shared__ float actsL[16][16][32];  // 32 KB raw acts slab, all banks
    __shared__ float asrcL[4][16][32];   // normalized sources
    __shared__ float accL[4][16][32];    // per-edge contributions
    __shared__ float gateL[4][16];
    __shared__ float mML[4][32], ivL[4][32];
    __shared__ float tgL[16];
    int tid = threadIdx.x;
    int row0 = blockIdx.x * 16;
    int wv = tid >> 6, lane = tid & 63;
    int d = lane & 31, kh = lane >> 5;
    int slot = blockIdx.x & 15;
    float* stats = ws + O_STATS2;
    // phase 0: load input-bank acts, stats for bank 0
    for (int i = tid; i < 1024; i += 256) {
        int b = i >> 9, r = (i >> 5) & 15, dd = i & 31;
        actsL[b][r][dd] = ws[O_ACTS + ((size_t)b * BATCH + row0 + r) * DD + dd];
    }
    if (tid < 16) tgL[tid] = 0.f;
    __syncthreads();
    if (tid < 64) {
        int dd = tid & 31, kind = tid >> 5;
        float s = 0.f;
        for (int r = 0; r < 16; r++) { float v = actsL[0][r][dd]; s += kind ? v * v : v; }
        atomicAdd(&stats[(size_t)slot * 64 + tid], s);
    }
    grid.sync();
    for (int t = 1; t < NB; t++) {
        int nE = t < 4 ? t : 4;
        int s0 = t - nE;
        int eb = (t <= 4) ? t * (t - 1) / 2 : 10 + 4 * (t - 5);
        if (tid < nE * 32) {
            int si = tid >> 5, dd = tid & 31;
            volatile float* st = stats + (size_t)(s0 + si) * 16 * 64;
            float sm = 0.f, sq = 0.f;
            for (int sl = 0; sl < 16; sl++) { sm += st[sl * 64 + dd]; sq += st[sl * 64 + 32 + dd]; }
            float m = sm * (1.f / BATCH);
            float var = sq * (1.f / BATCH) - m * m;
            mML[si][dd] = m;
            ivL[si][dd] = rsqrtf(fmaxf(var, 0.f) + BNEPS);
        }
        __syncthreads();
        for (int i = tid; i < nE * 512; i += 256) {
            int si = i >> 9, r = (i >> 5) & 15, dd = i & 31;
            asrcL[si][r][dd] = (actsL[s0 + si][r][dd] - mML[si][dd]) * ivL[si][dd];
        }
        __syncthreads();
        if (wv < nE) {
            int e = eb + wv;
            float wdr[16];
#pragma unroll
            for (int j = 0; j < 16; j++) wdr[j] = Wd[(size_t)e * 1024 + (size_t)(kh * 16 + j) * 32 + d];
            float wgr = Wg[e * 32 + d];
            float bdr = bd[e * 32 + d];
            for (int r = 0; r < 16; r++) {
                float g = asrcL[wv][r][d] * wgr;
                g += __shfl_xor(g, 1); g += __shfl_xor(g, 2); g += __shfl_xor(g, 4);
                g += __shfl_xor(g, 8); g += __shfl_xor(g, 16);
                g = fminf(fmaxf(g, 0.f), 1.f);
                float dat = 0.f;
                const float* ar = &asrcL[wv][r][kh * 16];
#pragma unroll
                for (int j = 0; j < 16; j += 4) {
                    float4 a4 = *(const float4*)(ar + j);
                    dat += a4.x * wdr[j] + a4.y * wdr[j + 1] + a4.z * wdr[j + 2] + a4.w * wdr[j + 3];
                }
                dat += __shfl_xor(dat, 32);
                float contrib = g * (dat + bdr);
                if (kh == 0) {
                    accL[wv][r][d] = contrib;
                    if (d == 0) gateL[wv][r] = g;
                }
            }
        }
        __syncthreads();
        for (int p = tid; p < 512; p += 256) {
            int r = p >> 5, dd = p & 31;
            float a = (t == 1) ? actsL[1][r][dd] : 0.f;
            for (int ei = 0; ei < nE; ei++) a += accL[ei][r][dd];
            float v = fmaxf(a, 0.f);
            actsL[t][r][dd] = v;
            if (t >= 14)
                ws[O_ACTS14 + ((size_t)(t - 14) * BATCH + row0 + r) * DD + dd] = v;
        }
        if (tid < 16) {
            float s = 0.f;
            for (int ei = 0; ei < nE; ei++) s += gateL[ei][tid];
            tgL[tid] += s;
        }
        __syncthreads();
        if (tid < 64) {
            int dd = tid & 31, kind = tid >> 5;
            float s = 0.f;
            for (int r = 0; r < 16; r++) { float v = actsL[t][r][dd]; s += kind ? v * v : v; }
            atomicAdd(&stats[((size_t)t * 16 + slot) * 64 + tid], s);
        }
        if (t < 15) grid.sync();
    }
    if (tid < 16) ws[O_TG + row0 + tid] = tgL[tid];
}

// ---- K7: output GEMM [8192x64]@[64x1000] -> f32 out; copy total_gate ----
__global__ void __launch_bounds__(256) k_out(const float* __restrict__ ws, const float* __restrict__ Wout,
                                             float* __restrict__ out) {
    __shared__ float aL[2][32][32];
    __shared__ float wl[2][32][128];
    int tid = threadIdx.x;
    int rg = tid >> 5, d = tid & 31;
    int row0 = blockIdx.x * 32;
    if (tid < 32) out[TGOFF + row0 + tid] = ws[O_TG + row0 + tid];
#pragma unroll
    for (int bi = 0; bi < 2; bi++) {
        const float* st = ws + O_STATS2 + (size_t)(14 + bi) * 16 * 64;
        float sm = 0.f, sq = 0.f;
        for (int sl = 0; sl < 16; sl++) { sm += st[sl * 64 + d]; sq += st[sl * 64 + 32 + d]; }
        float m = sm * (1.f / BATCH);
        float var = sq * (1.f / BATCH) - m * m;
        float iv = rsqrtf(fmaxf(var, 0.f) + BNEPS);
#pragma unroll
        for (int c = 0; c < 4; c++) {
            int r = c * 8 + rg;
            aL[bi][r][d] = (ws[O_ACTS14 + ((size_t)bi * BATCH + row0 + r) * DD + d] - m) * iv;
        }
    }
    __syncthreads();
    int nn = tid & 127, half = tid >> 7;
    for (int nc = 0; nc < 8; nc++) {
        int n = nc * 128 + nn;
        for (int i = 0; i < 32; i++) {
            int kbk = i * 2 + half;
            int kb = kbk >> 5, k = kbk & 31;
            if (n < NOUT) wl[kb][k][nn] = Wout[(size_t)kb * DD * NOUT + (size_t)k * NOUT + n];
        }
        __syncthreads();
#pragma unroll
        for (int rc = 0; rc < 2; rc++) {
            int rb = half * 16 + rc * 8;
            float acc[8] = {0.f, 0.f, 0.f, 0.f, 0.f, 0.f, 0.f, 0.f};
            for (int k = 0; k < 32; k++) {
                float w0 = wl[0][k][nn], w1 = wl[1][k][nn];
#pragma unroll
                for (int rr = 0; rr < 8; rr++)
                    acc[rr] += aL[0][rb + rr][k] * w0 + aL[1][rb + rr][k] * w1;
            }
            if (n < NOUT) {
#pragma unroll
                for (int rr = 0; rr < 8; rr++)
                    out[(size_t)(row0 + rb + rr) * NOUT + n] = acc[rr];
            }
        }
        __syncthreads();
    }
}

extern "C" void kernel_launch(void* const* d_in, const int* in_sizes, int n_in,
                              void* d_out, int out_size, void* d_ws, size_t ws_size,
                              hipStream_t stream) {
    (void)in_sizes; (void)n_in; (void)out_size; (void)ws_size;
    const float* x     = (const float*)d_in[0];
    const float* gamma = (const float*)d_in[1];
    const float* beta  = (const float*)d_in[2];
    const float* W_in  = (const float*)d_in[3];
    const float* b_in  = (const float*)d_in[4];
    const float* Wg    = (const float*)d_in[5];
    const float* Wd    = (const float*)d_in[6];
    const float* bd    = (const float*)d_in[7];
    const float* Wout  = (const float*)d_in[8];
    float* out = (float*)d_out;
    float* ws  = (float*)d_ws;

    hipMemsetAsync(d_ws, 0, ZERO_FLOATS * sizeof(float), stream);
    k_stats<<<dim3(12, 128), 256, 0, stream>>>(x, ws);
    k_prep<<<12, 256, 0, stream>>>(ws, gamma, beta, b_in);
    k_bias<<<24, 256, 0, stream>>>(ws, W_in);
    k_bfold<<<768, 256, 0, stream>>>(ws, W_in);
    k_gemm2<<<dim3(256, 2), 128, 0, stream>>>(x, ws);
    k_act<<<512, 256, 0, stream>>>(ws);
    {
        void* args[] = { (void*)&ws, (void*)&Wg, (void*)&Wd, (void*)&bd };
        hipLaunchCooperativeKernel((void*)k_graph, dim3(512), dim3(256), args, 0, stream);
    }
    k_out<<<256, 256, 0, stream>>>(ws, Wout, out);
}

// Round 6
// 503.407 us; speedup vs baseline: 2.8555x; 2.8555x over previous
//
#include <hip/hip_runtime.h>

// RouteNet f32. Structure: stats -> prep -> bias/bfold -> k_gemm3(K-split-4, no atomics)
// -> k_act(reduce+bias+relu) -> 16x k_bank (launch boundary = BN barrier) -> k_out.
// Round 6: reverted cooperative kernel (grid.sync cost ~67us/sync, round-5 lesson).
// k_bank widened to 1024 blocks x 8 rows for latency hiding; gemm register-tiled 4x4.

#define BATCH 8192
#define NIN 3072
#define DD 32
#define NB 16
#define NOUT 1000
#define TGOFF (BATCH * NOUT)
#define BNEPS 1e-5f

// ws float offsets
#define O_SUM 0          // [3072]
#define O_SUM2 3072      // [3072]
#define O_STATS2 6144    // [16 banks][16 slots][64] sum/sumsq
#define O_TG 22528       // [8192]
#define ZERO_FLOATS 30720
#define O_SCALE 30720    // [3072]
#define O_SHIFT 33792    // [3072]
#define O_BIAS 36864     // [64]
#define O_BP 36928       // [3072][64] folded B'
#define O_ACTS 233536    // [16][8192][32] raw acts (f32)
// O_ACC reuses acts banks 2..9 (dead until k_bank t=2, which runs after k_act)
#define O_ACC (O_ACTS + 2 * BATCH * DD)   // [4][8192][64] gemm partials
// total ws = 233536 + 16*8192*32 = 4,427,840 floats (~16.9 MB)

// ---- K1: column stats of x ----
__global__ void __launch_bounds__(256) k_stats(const float* __restrict__ x, float* __restrict__ ws) {
    int c = blockIdx.x * 256 + threadIdx.x;                  // 12 x-blocks
    const float* p = x + (size_t)blockIdx.y * 256 * NIN + c; // 32 y-blocks x 256 rows
    float s = 0.f, s2 = 0.f;
#pragma unroll 8
    for (int i = 0; i < 256; i++) { float v = p[(size_t)i * NIN]; s += v; s2 += v * v; }
    atomicAdd(&ws[O_SUM + c], s);
    atomicAdd(&ws[O_SUM2 + c], s2);
}

// ---- K2: scale/shift; seed fused bias with b_in ----
__global__ void __launch_bounds__(256) k_prep(float* __restrict__ ws, const float* __restrict__ g,
                                              const float* __restrict__ b, const float* __restrict__ b_in) {
    int c = blockIdx.x * 256 + threadIdx.x;
    float mean = ws[O_SUM + c] * (1.f / BATCH);
    float var = ws[O_SUM2 + c] * (1.f / BATCH) - mean * mean;
    float sc = g[c] * rsqrtf(fmaxf(var, 0.f) + BNEPS);
    ws[O_SCALE + c] = sc;
    ws[O_SHIFT + c] = b[c] - mean * sc;
    if (c < 64) ws[O_BIAS + c] = b_in[c];
}

// ---- K3a: bias' += shift @ W_in ----
__global__ void __launch_bounds__(256) k_bias(float* __restrict__ ws, const float* __restrict__ W_in) {
    int bank = blockIdx.x & 1, jc = blockIdx.x >> 1;
    int d = threadIdx.x & 31, js = threadIdx.x >> 5;
    int j0 = jc * 256 + js * 32;
    float a = 0.f;
    for (int j = 0; j < 32; j++)
        a += ws[O_SHIFT + j0 + j] * W_in[(size_t)bank * NIN * DD + (size_t)(j0 + j) * DD + d];
    __shared__ float red[8][32];
    red[js][d] = a;
    __syncthreads();
    if (threadIdx.x < 32) {
        float t = 0.f;
#pragma unroll
        for (int g8 = 0; g8 < 8; g8++) t += red[g8][threadIdx.x];
        atomicAdd(&ws[O_BIAS + bank * 32 + threadIdx.x], t);
    }
}

// ---- K3b: B'[j][c] = scale[j] * W_in[c>>5][j][c&31] ----
__global__ void __launch_bounds__(256) k_bfold(float* __restrict__ ws, const float* __restrict__ W_in) {
    int idx = blockIdx.x * 256 + threadIdx.x;
    int j = idx >> 6, c = idx & 63;
    ws[O_BP + idx] = ws[O_SCALE + j] * W_in[(size_t)(c >> 5) * NIN * DD + (size_t)j * DD + (c & 31)];
}

// ---- K4: input GEMM. grid (128,4): 64 rows x 64 cols per block, K-split 4 (768 each). ----
__global__ void __launch_bounds__(256) k_gemm3(const float* __restrict__ x, float* __restrict__ ws) {
    __shared__ float xL[64][20];   // 16 k + pad4
    __shared__ float bL[16][64];
    int tid = threadIdx.x;
    int row0 = blockIdx.x * 64;
    int k00 = blockIdx.y * 768;
    const float* bp = ws + O_BP;
    float acc[4][4] = {};
    int tx = tid & 15, rt = tid >> 4;      // cols tx*4, rows rt*4
    int lr = tid >> 2, lq = tid & 3;       // x loader
    int br = tid >> 4, bq = tid & 15;      // b loader
    for (int kc = 0; kc < 48; kc++) {
        int k0 = k00 + kc * 16;
        float4 xv = *(const float4*)&x[(size_t)(row0 + lr) * NIN + k0 + lq * 4];
        float4 bv = *(const float4*)&bp[(size_t)(k0 + br) * 64 + bq * 4];
        __syncthreads();
        *(float4*)&xL[lr][lq * 4] = xv;
        *(float4*)&bL[br][bq * 4] = bv;
        __syncthreads();
#pragma unroll
        for (int kk = 0; kk < 16; kk += 4) {
            float4 b0 = *(float4*)&bL[kk][tx * 4];
            float4 b1 = *(float4*)&bL[kk + 1][tx * 4];
            float4 b2 = *(float4*)&bL[kk + 2][tx * 4];
            float4 b3 = *(float4*)&bL[kk + 3][tx * 4];
#pragma unroll
            for (int j = 0; j < 4; j++) {
                float4 xv4 = *(float4*)&xL[rt * 4 + j][kk];
                acc[j][0] += xv4.x * b0.x + xv4.y * b1.x + xv4.z * b2.x + xv4.w * b3.x;
                acc[j][1] += xv4.x * b0.y + xv4.y * b1.y + xv4.z * b2.y + xv4.w * b3.y;
                acc[j][2] += xv4.x * b0.z + xv4.y * b1.z + xv4.z * b2.z + xv4.w * b3.z;
                acc[j][3] += xv4.x * b0.w + xv4.y * b1.w + xv4.z * b2.w + xv4.w * b3.w;
            }
        }
    }
    float* dst = ws + O_ACC + (size_t)blockIdx.y * (BATCH * 64);
#pragma unroll
    for (int j = 0; j < 4; j++) {
        float4 v = make_float4(acc[j][0], acc[j][1], acc[j][2], acc[j][3]);
        *(float4*)&dst[(size_t)(row0 + rt * 4 + j) * 64 + tx * 4] = v;
    }
}

// ---- K5: reduce 4 K-split partials + bias + relu -> acts banks 0/1 ----
__global__ void __launch_bounds__(256) k_act(float* __restrict__ ws) {
    int i4 = (blockIdx.x * 256 + threadIdx.x) * 4;  // 512 blocks cover 8192*64
    const float* ac = ws + O_ACC;
    float4 s0 = *(const float4*)&ac[i4];
    float4 s1 = *(const float4*)&ac[524288 + i4];
    float4 s2 = *(const float4*)&ac[1048576 + i4];
    float4 s3 = *(const float4*)&ac[1572864 + i4];
    int c = i4 & 63, row = i4 >> 6;
    const float* bias = ws + O_BIAS;
    float4 v;
    v.x = fmaxf(s0.x + s1.x + s2.x + s3.x + bias[c], 0.f);
    v.y = fmaxf(s0.y + s1.y + s2.y + s3.y + bias[c + 1], 0.f);
    v.z = fmaxf(s0.z + s1.z + s2.z + s3.z + bias[c + 2], 0.f);
    v.w = fmaxf(s0.w + s1.w + s2.w + s3.w + bias[c + 3], 0.f);
    int bank = c >> 5, dd = c & 31;
    *(float4*)&ws[O_ACTS + ((size_t)bank * BATCH + row) * DD + dd] = v;
}

// ---- K6 (x16): one bank. 1024 blocks x 8 rows; Wd prefetched; scalar accumulator. ----
__global__ void __launch_bounds__(256) k_bank(int t, float* __restrict__ ws,
                                              const float* __restrict__ Wg, const float* __restrict__ Wd,
                                              const float* __restrict__ bd) {
    __shared__ float asrcL[4][8][32];
    __shared__ float WdL[4][1024];
    __shared__ float mML[4][32], ivL[4][32];
    __shared__ float red[8][64];
    int tid = threadIdx.x;
    int rg = tid >> 5, d = tid & 31;
    int row0 = blockIdx.x * 8;
    int slot = blockIdx.x & 15;
    float* acts = ws + O_ACTS;
    float* stats = ws + O_STATS2;
    int nE = t < 4 ? t : 4;
    int s0 = t - nE;
    int eb = (t <= 4) ? t * (t - 1) / 2 : 10 + 4 * (t - 5);
    // prefetch all edge Wd (contiguous) into LDS
    for (int p = tid; p < nE * 256; p += 256)
        ((float4*)&WdL[0][0])[p] = ((const float4*)(Wd + (size_t)eb * 1024))[p];
    // per-edge Wg/bd rows into registers (const-indexed)
    float wgr[4], bdr[4];
#pragma unroll
    for (int ei = 0; ei < 4; ei++) {
        wgr[ei] = (ei < nE) ? Wg[(eb + ei) * 32 + d] : 0.f;
        bdr[ei] = (ei < nE) ? bd[(eb + ei) * 32 + d] : 0.f;
    }
    // source-bank BN params
    if (tid < nE * 32) {
        int si = tid >> 5, dd = tid & 31;
        const float* st = stats + (size_t)(s0 + si) * 16 * 64;
        float sm = 0.f, sq = 0.f;
#pragma unroll
        for (int sl = 0; sl < 16; sl++) { sm += st[sl * 64 + dd]; sq += st[sl * 64 + 32 + dd]; }
        float m = sm * (1.f / BATCH);
        float var = sq * (1.f / BATCH) - m * m;
        mML[si][dd] = m;
        ivL[si][dd] = rsqrtf(fmaxf(var, 0.f) + BNEPS);
    }
    float cur = (t < 2) ? acts[((size_t)t * BATCH + row0 + rg) * DD + d] : 0.f;
    __syncthreads();
#pragma unroll 4
    for (int si = 0; si < nE; si++)
        asrcL[si][rg][d] = (acts[((size_t)(s0 + si) * BATCH + row0 + rg) * DD + d] - mML[si][d]) * ivL[si][d];
    __syncthreads();
    float tg = 0.f;
#pragma unroll
    for (int ei = 0; ei < 4; ei++) {
        if (ei < nE) {
            float g = asrcL[ei][rg][d] * wgr[ei];
            g += __shfl_xor(g, 1); g += __shfl_xor(g, 2); g += __shfl_xor(g, 4);
            g += __shfl_xor(g, 8); g += __shfl_xor(g, 16);
            g = fminf(fmaxf(g, 0.f), 1.f);
            tg += g;
            float dat = bdr[ei];
            const float* ar = asrcL[ei][rg];
            const float* wc = &WdL[ei][d];
#pragma unroll
            for (int k = 0; k < 32; k += 4) {
                float4 a4 = *(const float4*)&ar[k];
                dat += a4.x * wc[k * 32] + a4.y * wc[(k + 1) * 32]
                     + a4.z * wc[(k + 2) * 32] + a4.w * wc[(k + 3) * 32];
            }
            cur += g * dat;
        }
    }
    float v = fmaxf(cur, 0.f);
    acts[((size_t)t * BATCH + row0 + rg) * DD + d] = v;
    if (d == 0 && nE > 0) ws[O_TG + row0 + rg] += tg;
    red[rg][d] = v; red[rg][32 + d] = v * v;
    __syncthreads();
    if (tid < 64) {
        float a = 0.f;
#pragma unroll
        for (int g8 = 0; g8 < 8; g8++) a += red[g8][tid];
        atomicAdd(&stats[((size_t)t * 16 + slot) * 64 + tid], a);
    }
}

// ---- K7: output GEMM [8192x64]@[64x1000] -> f32 out; copy total_gate ----
__global__ void __launch_bounds__(256) k_out(const float* __restrict__ ws, const float* __restrict__ Wout,
                                             float* __restrict__ out) {
    __shared__ float aL[2][32][32];
    __shared__ float wl[2][32][128];
    int tid = threadIdx.x;
    int rg = tid >> 5, d = tid & 31;
    int row0 = blockIdx.x * 32;
    const float* acts = ws + O_ACTS;
    if (tid < 32) out[TGOFF + row0 + tid] = ws[O_TG + row0 + tid];
#pragma unroll
    for (int bi = 0; bi < 2; bi++) {
        const float* st = ws + O_STATS2 + (size_t)(14 + bi) * 16 * 64;
        float sm = 0.f, sq = 0.f;
#pragma unroll
        for (int sl = 0; sl < 16; sl++) { sm += st[sl * 64 + d]; sq += st[sl * 64 + 32 + d]; }
        float m = sm * (1.f / BATCH);
        float var = sq * (1.f / BATCH) - m * m;
        float iv = rsqrtf(fmaxf(var, 0.f) + BNEPS);
#pragma unroll
        for (int c = 0; c < 4; c++) {
            int r = c * 8 + rg;
            aL[bi][r][d] = (acts[((size_t)(14 + bi) * BATCH + row0 + r) * DD + d] - m) * iv;
        }
    }
    __syncthreads();
    int nn = tid & 127, half = tid >> 7;
    for (int nc = 0; nc < 8; nc++) {
        int n = nc * 128 + nn;
        for (int i = 0; i < 32; i++) {
            int kbk = i * 2 + half;
            int kb = kbk >> 5, k = kbk & 31;
            if (n < NOUT) wl[kb][k][nn] = Wout[(size_t)kb * DD * NOUT + (size_t)k * NOUT + n];
        }
        __syncthreads();
#pragma unroll
        for (int rc = 0; rc < 2; rc++) {
            int rb = half * 16 + rc * 8;
            float acc[8] = {0.f, 0.f, 0.f, 0.f, 0.f, 0.f, 0.f, 0.f};
            for (int k = 0; k < 32; k++) {
                float w0 = wl[0][k][nn], w1 = wl[1][k][nn];
#pragma unroll
                for (int rr = 0; rr < 8; rr++)
                    acc[rr] += aL[0][rb + rr][k] * w0 + aL[1][rb + rr][k] * w1;
            }
            if (n < NOUT) {
#pragma unroll
                for (int rr = 0; rr < 8; rr++)
                    out[(size_t)(row0 + rb + rr) * NOUT + n] = acc[rr];
            }
        }
        __syncthreads();
    }
}

extern "C" void kernel_launch(void* const* d_in, const int* in_sizes, int n_in,
                              void* d_out, int out_size, void* d_ws, size_t ws_size,
                              hipStream_t stream) {
    (void)in_sizes; (void)n_in; (void)out_size; (void)ws_size;
    const float* x     = (const float*)d_in[0];
    const float* gamma = (const float*)d_in[1];
    const float* beta  = (const float*)d_in[2];
    const float* W_in  = (const float*)d_in[3];
    const float* b_in  = (const float*)d_in[4];
    const float* Wg    = (const float*)d_in[5];
    const float* Wd    = (const float*)d_in[6];
    const float* bd    = (const float*)d_in[7];
    const float* Wout  = (const float*)d_in[8];
    float* out = (float*)d_out;
    float* ws  = (float*)d_ws;

    hipMemsetAsync(d_ws, 0, ZERO_FLOATS * sizeof(float), stream);
    k_stats<<<dim3(12, 32), 256, 0, stream>>>(x, ws);
    k_prep<<<12, 256, 0, stream>>>(ws, gamma, beta, b_in);
    k_bias<<<24, 256, 0, stream>>>(ws, W_in);
    k_bfold<<<768, 256, 0, stream>>>(ws, W_in);
    k_gemm3<<<dim3(128, 4), 256, 0, stream>>>(x, ws);
    k_act<<<512, 256, 0, stream>>>(ws);
    for (int t = 0; t < NB; t++)
        k_bank<<<1024, 256, 0, stream>>>(t, ws, Wg, Wd, bd);
    k_out<<<256, 256, 0, stream>>>(ws, Wout, out);
}